// Round 13
// baseline (190.429 us; speedup 1.0000x reference)
//
#include <hip/hip_runtime.h>
#include <hip/hip_bf16.h>

#define A_N   2048
#define D_N   64
#define FL_N  12
#define KTOT  (A_N * FL_N)          // 24576
#define S_SPLIT 16
#define KCHUNK 1536                 // cols per kc-chunk (KTOT/16)
#define NBK   12                    // KCHUNK/128
#define TILE_B 16384                // 64 rows * 128 k * 2B

typedef __attribute__((ext_vector_type(8))) short bf16x8;  // 8 bf16 = 4 VGPRs
typedef __attribute__((ext_vector_type(4))) short bf16x4;  // 8 B
typedef __attribute__((ext_vector_type(4))) float f32x4;

__device__ __forceinline__ short f2bf(float f) {
  union { __hip_bfloat16 b; short s; } u;
  u.b = __float2bfloat16(f);
  return u.s;
}

// ---------- fused setup + conn conversion (tiled layout) ----------
// connb2: tile(rt,kc,bk) = contiguous 16 KB = [row r 0..63][k 0..127] bf16.
// blocks [0,192): P2; [192,704): bond; [704,4800): connb2 tiles.
__global__ void k_setup_cvt(const float* __restrict__ pf0, const float* __restrict__ bf0,
                            const float* __restrict__ pf1, const float* __restrict__ bf1,
                            const float* __restrict__ bp,
                            const float* __restrict__ conn,
                            short* __restrict__ P2_0, short* __restrict__ P2_1,
                            float* __restrict__ bond0, float* __restrict__ bond1,
                            short* __restrict__ connb2) {
  int b = blockIdx.x, t = threadIdx.x;
  if (b >= 704) {
    size_t slot = (size_t)(b - 704) * 256 + t;        // < 1048576
#pragma unroll
    for (int cc = 0; cc < 6; ++cc) {
      size_t i = (slot + (size_t)cc * 1048576) * 8;   // covers 50331648 floats exactly
      f32x4 a0 = __builtin_nontemporal_load((const f32x4*)(conn + i));
      f32x4 a1 = __builtin_nontemporal_load((const f32x4*)(conn + i + 4));
      bf16x8 v;
      v[0]=f2bf(a0[0]); v[1]=f2bf(a0[1]); v[2]=f2bf(a0[2]); v[3]=f2bf(a0[3]);
      v[4]=f2bf(a1[0]); v[5]=f2bf(a1[1]); v[6]=f2bf(a1[2]); v[7]=f2bf(a1[3]);
      int a = (int)(i / KTOT), c = (int)(i % KTOT);   // k = c&127 multiple of 8
      int rt = a >> 6, r = a & 63;
      int kc = c / KCHUNK, rem = c % KCHUNK;
      int bk = rem >> 7, k = rem & 127;
      size_t dst = ((size_t)((rt * 16 + kc) * NBK + bk) << 14) + (r << 8) + (k << 1);
      *(bf16x8*)((char*)connb2 + dst) = v;
    }
    return;
  }
  if (b < 192) {
    int idx = b * 256 + t;                       // < 49152
    int f = (idx >> 6) % FL_N;
    int o = idx / (D_N * FL_N);
    P2_0[idx] = f2bf(pf0[idx] * bf0[(o * FL_N + f) * 3]);
    P2_1[idx] = f2bf(pf1[idx] * bf1[(o * FL_N + f) * 3]);
  } else {
    int o = t & 63;
    int a = (b - 192) * 4 + (t >> 6);
    float s0 = 0.f, s1 = 0.f;
#pragma unroll
    for (int f = 0; f < FL_N; ++f) {
      float c0 = bp[(a * FL_N + f) * 2 + 0];
      float c1 = bp[(a * FL_N + f) * 2 + 1];
      s0 += c0 * bf0[(o * FL_N + f) * 3 + 1] + c1 * bf0[(o * FL_N + f) * 3 + 2];
      s1 += c0 * bf1[(o * FL_N + f) * 3 + 1] + c1 * bf1[(o * FL_N + f) * 3 + 2];
    }
    bond0[a * D_N + o] = s0;
    bond1[a * D_N + o] = s1;
  }
}

// ---------- Bt prep (shared MFMA body, R9 layout) ----------
// Bt2: slab(kc,bk) = contiguous 16 KB = [o 0..63][k 0..127] bf16 (row-major).
__device__ __forceinline__ void prep_body(bf16x8 h0, bf16x8 h1,
                                          const short* __restrict__ P2,
                                          short* __restrict__ Bt2,
                                          int k0, int lane, int w) {
  int l15 = lane & 15, grp = lane >> 4;
  const short* prow = P2 + (w * 16 + l15) * (FL_N * D_N) + grp * 8;
  f32x4 acc[FL_N];
#pragma unroll
  for (int f = 0; f < FL_N; ++f) {
    bf16x8 p0 = *(const bf16x8*)(prow + f * D_N);
    bf16x8 p1 = *(const bf16x8*)(prow + f * D_N + 32);
    f32x4 c = {0.f, 0.f, 0.f, 0.f};
    c = __builtin_amdgcn_mfma_f32_16x16x32_bf16(p0, h0, c, 0, 0, 0);
    c = __builtin_amdgcn_mfma_f32_16x16x32_bf16(p1, h1, c, 0, 0, 0);
    acc[f] = c;
  }
  // D layout: row(o) = grp*4 + r (+w*16), col(katom) = l15 (+k0)
#pragma unroll
  for (int r = 0; r < 4; ++r) {
    int o = w * 16 + grp * 4 + r;
    int katom = k0 + l15;
#pragma unroll
    for (int f = 0; f < FL_N; ++f) {
      int c = katom * FL_N + f;
      int kc = c / KCHUNK, rem = c % KCHUNK;
      int bk = rem >> 7, k = rem & 127;
      *(short*)((char*)Bt2 + ((size_t)(kc * NBK + bk) << 14) + (o << 8) + (k << 1))
          = f2bf(acc[f][r]);
    }
  }
}

// prep for conv0: reads x (f32) directly, converts in-kernel
__global__ void k_prep0(const float* __restrict__ x, const short* __restrict__ P2,
                        short* __restrict__ Bt2) {
  int lane = threadIdx.x & 63, w = threadIdx.x >> 6;
  int l15 = lane & 15, grp = lane >> 4;
  int k0 = blockIdx.x * 16;
  const float* hrow = x + (k0 + l15) * D_N + grp * 8;
  f32x4 x0 = *(const f32x4*)(hrow);
  f32x4 x1 = *(const f32x4*)(hrow + 4);
  f32x4 x2 = *(const f32x4*)(hrow + 32);
  f32x4 x3 = *(const f32x4*)(hrow + 36);
  bf16x8 h0, h1;
  h0[0]=f2bf(x0[0]); h0[1]=f2bf(x0[1]); h0[2]=f2bf(x0[2]); h0[3]=f2bf(x0[3]);
  h0[4]=f2bf(x1[0]); h0[5]=f2bf(x1[1]); h0[6]=f2bf(x1[2]); h0[7]=f2bf(x1[3]);
  h1[0]=f2bf(x2[0]); h1[1]=f2bf(x2[1]); h1[2]=f2bf(x2[2]); h1[3]=f2bf(x2[3]);
  h1[4]=f2bf(x3[0]); h1[5]=f2bf(x3[1]); h1[6]=f2bf(x3[2]); h1[7]=f2bf(x3[3]);
  prep_body(h0, h1, P2, Bt2, k0, lane, w);
}

// prep for conv c>0: reads hb (bf16, produced by k_reduce)
__global__ void k_prepH(const short* __restrict__ hb, const short* __restrict__ P2,
                        short* __restrict__ Bt2) {
  int lane = threadIdx.x & 63, w = threadIdx.x >> 6;
  int l15 = lane & 15, grp = lane >> 4;
  int k0 = blockIdx.x * 16;
  const short* hrow = hb + (k0 + l15) * D_N + grp * 8;
  bf16x8 h0 = *(const bf16x8*)(hrow);
  bf16x8 h1 = *(const bf16x8*)(hrow + 32);
  prep_body(h0, h1, P2, Bt2, k0, lane, w);
}

// ---------- split-K reduce -> relu -> hb (bf16); 512 blocks, pure streaming ----------
template <int ADDX>
__global__ void k_reduce(const float* __restrict__ part, const float* __restrict__ bond,
                         const float* __restrict__ x, short* __restrict__ hb) {
  int i = blockIdx.x * 256 + threadIdx.x;   // 131072 total
  float s = bond[i];
#pragma unroll
  for (int si = 0; si < S_SPLIT; ++si) s += part[(size_t)si * (A_N * D_N) + i];
  if (ADDX) s += x[i];
  hb[i] = f2bf(fmaxf(s, 0.f));
}

// ---------- big GEMM: R9's best (LDS dbuf, depth-2 reg prefetch, XOR swizzle) ----------
template <int C>
__global__ __launch_bounds__(256, 2) void k_gemm(const short* __restrict__ connb2,
                                                 const short* __restrict__ Bt2,
                                                 float* __restrict__ part) {
  __shared__ short lA[2][8192];   // 16 KB each buf: [row 64][k 128] swizzled
  __shared__ short lB[2][8192];
  int t = threadIdx.x;
  int lane = t & 63, w = t >> 6, l15 = lane & 15, grp = lane >> 4;
  int rt = blockIdx.x, kc = blockIdx.y;

  const char* Ab = (const char*)connb2 + (((size_t)(rt * 16 + kc) * NBK) << 14);
  const char* Bb = (const char*)Bt2 + (((size_t)kc * NBK) << 14);

  int ldsoff[4];
#pragma unroll
  for (int q = 0; q < 4; ++q) {
    int j = q * 256 + t;
    int row = j >> 4, cw = j & 15;
    ldsoff[q] = (row << 8) + ((cw << 4) ^ ((row & 7) << 4));
  }

  bf16x8 ra[2][4], rb[2][4];

#pragma unroll
  for (int q = 0; q < 4; ++q) {
    ra[0][q] = *(const bf16x8*)(Ab + q * 4096 + t * 16);
    rb[0][q] = *(const bf16x8*)(Bb + q * 4096 + t * 16);
  }
#pragma unroll
  for (int q = 0; q < 4; ++q) {
    ra[1][q] = *(const bf16x8*)(Ab + TILE_B + q * 4096 + t * 16);
    rb[1][q] = *(const bf16x8*)(Bb + TILE_B + q * 4096 + t * 16);
  }
#pragma unroll
  for (int q = 0; q < 4; ++q) {
    *(bf16x8*)((char*)&lA[0][0] + ldsoff[q]) = ra[0][q];
    *(bf16x8*)((char*)&lB[0][0] + ldsoff[q]) = rb[0][q];
  }
  __syncthreads();

  f32x4 acc0 = {0,0,0,0}, acc1 = {0,0,0,0}, acc2 = {0,0,0,0}, acc3 = {0,0,0,0};
  const int arow = (w * 16 + l15) << 8;
  const int brow = l15 << 8;
  const int key  = (l15 & 7) << 4;

#pragma unroll
  for (int bk = 0; bk < NBK; ++bk) {
    const int cur = bk & 1;
    const int nxt = cur ^ 1;
    if (bk + 2 < NBK) {
      const char* An = Ab + (size_t)(bk + 2) * TILE_B;
      const char* Bn = Bb + (size_t)(bk + 2) * TILE_B;
#pragma unroll
      for (int q = 0; q < 4; ++q) {
        ra[cur][q] = *(const bf16x8*)(An + q * 4096 + t * 16);
        rb[cur][q] = *(const bf16x8*)(Bn + q * 4096 + t * 16);
      }
    }
    const char* la = (const char*)&lA[cur][0];
    const char* lb = (const char*)&lB[cur][0];
#pragma unroll
    for (int ks = 0; ks < 4; ++ks) {
      const int cb = ((ks << 6) + (grp << 4)) ^ key;
      bf16x8 af = *(const bf16x8*)(la + arow + cb);
      bf16x8 b0 = *(const bf16x8*)(lb + brow + cb);
      bf16x8 b1 = *(const bf16x8*)(lb + 4096 + brow + cb);
      bf16x8 b2 = *(const bf16x8*)(lb + 8192 + brow + cb);
      bf16x8 b3 = *(const bf16x8*)(lb + 12288 + brow + cb);
      acc0 = __builtin_amdgcn_mfma_f32_16x16x32_bf16(af, b0, acc0, 0, 0, 0);
      acc1 = __builtin_amdgcn_mfma_f32_16x16x32_bf16(af, b1, acc1, 0, 0, 0);
      acc2 = __builtin_amdgcn_mfma_f32_16x16x32_bf16(af, b2, acc2, 0, 0, 0);
      acc3 = __builtin_amdgcn_mfma_f32_16x16x32_bf16(af, b3, acc3, 0, 0, 0);
    }
    if (bk + 1 < NBK) {
#pragma unroll
      for (int q = 0; q < 4; ++q) {
        *(bf16x8*)((char*)&lA[nxt][0] + ldsoff[q]) = ra[nxt][q];
        *(bf16x8*)((char*)&lB[nxt][0] + ldsoff[q]) = rb[nxt][q];
      }
      __syncthreads();
    }
  }

  float* p = part + (size_t)kc * (A_N * D_N);
  int rbase = rt * 64 + w * 16 + grp * 4;
#pragma unroll
  for (int r = 0; r < 4; ++r) {
    float* pr = p + (size_t)(rbase + r) * D_N + l15;
    pr[0]  = acc0[r];
    pr[16] = acc1[r];
    pr[32] = acc2[r];
    pr[48] = acc3[r];
  }
}

// ---------- final reduce -> f32 out ----------
__global__ void k_final(const float* __restrict__ part, const float* __restrict__ bond,
                        const float* __restrict__ x, float* __restrict__ out) {
  int i = blockIdx.x * 256 + threadIdx.x;   // 131072 total
  float s = bond[i];
#pragma unroll
  for (int si = 0; si < S_SPLIT; ++si) s += part[(size_t)si * (A_N * D_N) + i];
  out[i] = fmaxf(s + x[i], 0.f);
}

// ---------- launch ----------
extern "C" void kernel_launch(void* const* d_in, const int* in_sizes, int n_in,
                              void* d_out, int out_size, void* d_ws, size_t ws_size,
                              hipStream_t stream) {
  const float* x    = (const float*)d_in[0];
  const float* conn = (const float*)d_in[1];
  const float* bprp = (const float*)d_in[2];
  const float* pf0  = (const float*)d_in[3];
  const float* bf0  = (const float*)d_in[4];
  const float* pf1  = (const float*)d_in[5];
  const float* bf1  = (const float*)d_in[6];
  float* out = (float*)d_out;

  char* ws = (char*)d_ws;
  size_t off = 0;
  short* connb2 = (short*)(ws + off); off += (size_t)A_N * KTOT * 2;           // 100.7 MB
  short* Bt2    = (short*)(ws + off); off += (size_t)D_N * KTOT * 2;           // 3 MB
  float* part   = (float*)(ws + off); off += (size_t)S_SPLIT * A_N * D_N * 4;  // 8.4 MB
  short* hb     = (short*)(ws + off); off += (size_t)A_N * D_N * 2;
  float* bond0  = (float*)(ws + off); off += (size_t)A_N * D_N * 4;
  float* bond1  = (float*)(ws + off); off += (size_t)A_N * D_N * 4;
  short* P2_0   = (short*)(ws + off); off += (size_t)D_N * FL_N * D_N * 2;
  short* P2_1   = (short*)(ws + off); off += (size_t)D_N * FL_N * D_N * 2;

  k_setup_cvt<<<4800, 256, 0, stream>>>(pf0, bf0, pf1, bf1, bprp, conn,
                                        P2_0, P2_1, bond0, bond1, connb2);

  dim3 ggrid(32, S_SPLIT);

  // conv0: h = x
  k_prep0<<<128, 256, 0, stream>>>(x, P2_0, Bt2);
  k_gemm<0><<<ggrid, 256, 0, stream>>>(connb2, Bt2, part);

  // conv1: h1 = relu(conv0); bond0; P2_0
  k_reduce<0><<<512, 256, 0, stream>>>(part, bond0, x, hb);
  k_prepH<<<128, 256, 0, stream>>>(hb, P2_0, Bt2);
  k_gemm<1><<<ggrid, 256, 0, stream>>>(connb2, Bt2, part);

  // conv2: h2 = relu(conv1 + x); bond0; P2_1
  k_reduce<1><<<512, 256, 0, stream>>>(part, bond0, x, hb);
  k_prepH<<<128, 256, 0, stream>>>(hb, P2_1, Bt2);
  k_gemm<2><<<ggrid, 256, 0, stream>>>(connb2, Bt2, part);

  // conv3: h3 = relu(conv2); bond1; P2_1
  k_reduce<0><<<512, 256, 0, stream>>>(part, bond1, x, hb);
  k_prepH<<<128, 256, 0, stream>>>(hb, P2_1, Bt2);
  k_gemm<3><<<ggrid, 256, 0, stream>>>(connb2, Bt2, part);

  // out = relu(conv3 + bond1 + x)
  k_final<<<512, 256, 0, stream>>>(part, bond1, x, out);
}

// Round 14
// 178.498 us; speedup vs baseline: 1.0668x; 1.0668x over previous
//
#include <hip/hip_runtime.h>
#include <hip/hip_bf16.h>

#define A_N   2048
#define D_N   64
#define FL_N  12
#define KTOT  (A_N * FL_N)          // 24576
#define S_SPLIT 16
#define KCHUNK 1536                 // cols per kc-chunk (KTOT/16)
#define NBK   12                    // KCHUNK/128
#define TILE_A 8192                 // 64 rows * 128 k * 1B (i8)
#define SLAB_B 16384                // Btq slab: [hi 8KB][lo 8KB]

typedef __attribute__((ext_vector_type(8))) short bf16x8;  // generic 16 B
typedef __attribute__((ext_vector_type(4))) short bf16x4;
typedef __attribute__((ext_vector_type(4))) float f32x4;
typedef __attribute__((ext_vector_type(4))) int   i32x4;
typedef __attribute__((ext_vector_type(8))) char  i8x8;

__device__ __forceinline__ short f2bf(float f) {
  union { __hip_bfloat16 b; short s; } u;
  u.b = __float2bfloat16(f);
  return u.s;
}
__device__ __forceinline__ float bits2f(unsigned u) {
  union { unsigned u; float f; } c; c.u = u; return c.f;
}

// ---------- fused setup: P2, bond, conn -> i8 tiled+swizzled ----------
// connq: tile(rt,kc,bk) = 8 KB = [row r 0..63][k 0..127] i8; 16B chunk cw stored
// at physical chunk cw ^ (r&7)  (producer-side swizzle; LDS copy stays linear).
__global__ void k_setup_cvt(const float* __restrict__ pf0, const float* __restrict__ bf0,
                            const float* __restrict__ pf1, const float* __restrict__ bf1,
                            const float* __restrict__ bp,
                            const float* __restrict__ conn,
                            short* __restrict__ P2_0, short* __restrict__ P2_1,
                            float* __restrict__ bond0, float* __restrict__ bond1,
                            char* __restrict__ connq) {
  int b = blockIdx.x, t = threadIdx.x;
  if (b >= 704) {
    size_t slot = (size_t)(b - 704) * 256 + t;        // < 1048576
#pragma unroll
    for (int cc = 0; cc < 6; ++cc) {
      size_t i = (slot + (size_t)cc * 1048576) * 8;   // covers 50331648 floats exactly
      f32x4 a0 = __builtin_nontemporal_load((const f32x4*)(conn + i));
      f32x4 a1 = __builtin_nontemporal_load((const f32x4*)(conn + i + 4));
      i8x8 v;
      v[0]=(char)rintf(a0[0]*127.f); v[1]=(char)rintf(a0[1]*127.f);
      v[2]=(char)rintf(a0[2]*127.f); v[3]=(char)rintf(a0[3]*127.f);
      v[4]=(char)rintf(a1[0]*127.f); v[5]=(char)rintf(a1[1]*127.f);
      v[6]=(char)rintf(a1[2]*127.f); v[7]=(char)rintf(a1[3]*127.f);
      int a = (int)(i / KTOT), c = (int)(i % KTOT);   // c is 8-aligned
      int rt = a >> 6, r = a & 63;
      int kc = c / KCHUNK, rem = c % KCHUNK;
      int bk = rem >> 7, k = rem & 127;
      int phys = (k >> 4) ^ (r & 7);
      size_t dst = ((size_t)((rt * 16 + kc) * NBK + bk) << 13)
                   + (r << 7) + (phys << 4) + (k & 15);
      *(i8x8*)(connq + dst) = v;
    }
    return;
  }
  if (b < 192) {
    int idx = b * 256 + t;                       // < 49152
    int f = (idx >> 6) % FL_N;
    int o = idx / (D_N * FL_N);
    P2_0[idx] = f2bf(pf0[idx] * bf0[(o * FL_N + f) * 3]);
    P2_1[idx] = f2bf(pf1[idx] * bf1[(o * FL_N + f) * 3]);
  } else {
    int o = t & 63;
    int a = (b - 192) * 4 + (t >> 6);
    float s0 = 0.f, s1 = 0.f;
#pragma unroll
    for (int f = 0; f < FL_N; ++f) {
      float c0 = bp[(a * FL_N + f) * 2 + 0];
      float c1 = bp[(a * FL_N + f) * 2 + 1];
      s0 += c0 * bf0[(o * FL_N + f) * 3 + 1] + c1 * bf0[(o * FL_N + f) * 3 + 2];
      s1 += c0 * bf1[(o * FL_N + f) * 3 + 1] + c1 * bf1[(o * FL_N + f) * 3 + 2];
    }
    bond0[a * D_N + o] = s0;
    bond1[a * D_N + o] = s1;
  }
}

// ---------- Bt prep (bf16 MFMA, unchanged) -> Btb bf16 slabs [o][k] linear ----------
__device__ __forceinline__ void prep_body(bf16x8 h0, bf16x8 h1,
                                          const short* __restrict__ P2,
                                          short* __restrict__ Btb,
                                          int k0, int lane, int w) {
  int l15 = lane & 15, grp = lane >> 4;
  const short* prow = P2 + (w * 16 + l15) * (FL_N * D_N) + grp * 8;
  f32x4 acc[FL_N];
#pragma unroll
  for (int f = 0; f < FL_N; ++f) {
    bf16x8 p0 = *(const bf16x8*)(prow + f * D_N);
    bf16x8 p1 = *(const bf16x8*)(prow + f * D_N + 32);
    f32x4 c = {0.f, 0.f, 0.f, 0.f};
    c = __builtin_amdgcn_mfma_f32_16x16x32_bf16(p0, h0, c, 0, 0, 0);
    c = __builtin_amdgcn_mfma_f32_16x16x32_bf16(p1, h1, c, 0, 0, 0);
    acc[f] = c;
  }
#pragma unroll
  for (int r = 0; r < 4; ++r) {
    int o = w * 16 + grp * 4 + r;
    int katom = k0 + l15;
#pragma unroll
    for (int f = 0; f < FL_N; ++f) {
      int c = katom * FL_N + f;
      int kc = c / KCHUNK, rem = c % KCHUNK;
      int bk = rem >> 7, k = rem & 127;
      *(short*)((char*)Btb + ((size_t)(kc * NBK + bk) << 14) + (o << 8) + (k << 1))
          = f2bf(acc[f][r]);
    }
  }
}

__global__ void k_prep0(const float* __restrict__ x, const short* __restrict__ P2,
                        short* __restrict__ Btb) {
  int lane = threadIdx.x & 63, w = threadIdx.x >> 6;
  int l15 = lane & 15, grp = lane >> 4;
  int k0 = blockIdx.x * 16;
  const float* hrow = x + (k0 + l15) * D_N + grp * 8;
  f32x4 x0 = *(const f32x4*)(hrow);
  f32x4 x1 = *(const f32x4*)(hrow + 4);
  f32x4 x2 = *(const f32x4*)(hrow + 32);
  f32x4 x3 = *(const f32x4*)(hrow + 36);
  bf16x8 h0, h1;
  h0[0]=f2bf(x0[0]); h0[1]=f2bf(x0[1]); h0[2]=f2bf(x0[2]); h0[3]=f2bf(x0[3]);
  h0[4]=f2bf(x1[0]); h0[5]=f2bf(x1[1]); h0[6]=f2bf(x1[2]); h0[7]=f2bf(x1[3]);
  h1[0]=f2bf(x2[0]); h1[1]=f2bf(x2[1]); h1[2]=f2bf(x2[2]); h1[3]=f2bf(x2[3]);
  h1[4]=f2bf(x3[0]); h1[5]=f2bf(x3[1]); h1[6]=f2bf(x3[2]); h1[7]=f2bf(x3[3]);
  prep_body(h0, h1, P2, Btb, k0, lane, w);
}

__global__ void k_prepH(const short* __restrict__ hb, const short* __restrict__ P2,
                        short* __restrict__ Btb) {
  int lane = threadIdx.x & 63, w = threadIdx.x >> 6;
  int l15 = lane & 15, grp = lane >> 4;
  int k0 = blockIdx.x * 16;
  const short* hrow = hb + (k0 + l15) * D_N + grp * 8;
  bf16x8 h0 = *(const bf16x8*)(hrow);
  bf16x8 h1 = *(const bf16x8*)(hrow + 32);
  prep_body(h0, h1, P2, Btb, k0, lane, w);
}

// ---------- quantB: Btb bf16 -> dual-plane i8 (swizzled) + per-(o,kc) scale ----------
// block b: kc = b>>6, o = b&63; 64 threads; thread t handles k = 2t, 2t+1 per bk.
__global__ void k_quantB(const short* __restrict__ Btb, char* __restrict__ Btq,
                         float* __restrict__ sc) {
  int b = blockIdx.x, t = threadIdx.x;
  int kc = b >> 6, o = b & 63;
  float v0[NBK], v1[NBK];
  float m = 0.f;
#pragma unroll
  for (int bk = 0; bk < NBK; ++bk) {
    unsigned sv = *(const unsigned*)((const char*)Btb
                   + ((size_t)(kc * NBK + bk) << 14) + (o << 8) + (t << 2));
    float f0 = bits2f(sv << 16);
    float f1 = bits2f(sv & 0xFFFF0000u);
    v0[bk] = f0; v1[bk] = f1;
    m = fmaxf(m, fmaxf(fabsf(f0), fabsf(f1)));
  }
#pragma unroll
  for (int off = 1; off < 64; off <<= 1) m = fmaxf(m, __shfl_xor(m, off));
  float inv = (m > 1e-30f) ? (127.f / m) : 0.f;
  if (t == 0) sc[kc * 64 + o] = m * (1.f / 16129.f);   // m/(127*127)
  int k = 2 * t;
  int phys = ((k >> 4) ^ (o & 7));
  int boff = (o << 7) + (phys << 4) + (k & 15);
#pragma unroll
  for (int bk = 0; bk < NBK; ++bk) {
    float s0 = v0[bk] * inv, s1 = v1[bk] * inv;
    float h0 = rintf(s0), h1 = rintf(s1);
    char q0 = (char)h0, q1 = (char)h1;
    char l0 = (char)rintf((s0 - h0) * 127.f);
    char l1 = (char)rintf((s1 - h1) * 127.f);
    char* base = Btq + ((size_t)(kc * NBK + bk) << 14);
    *(short*)(base + boff) = (short)(((unsigned char)q0) | (((unsigned)(unsigned char)q1) << 8));
    *(short*)(base + 8192 + boff) = (short)(((unsigned char)l0) | (((unsigned)(unsigned char)l1) << 8));
  }
}

// ---------- big GEMM: i8 MFMA, LDS dbuf, depth-2 reg prefetch ----------
// Block (rt,kc): 64 rows x 1536 k; per bk: A tile 8 KB + B slab 16 KB (hi+lo).
// out = sc[o,kc] * (acc_hi + acc_lo/127); i32 accumulation exact.
template <int C>
__global__ __launch_bounds__(256, 2) void k_gemm(const char* __restrict__ connq,
                                                 const char* __restrict__ Btq,
                                                 const float* __restrict__ sc,
                                                 float* __restrict__ part) {
  __shared__ char lA[2][8192];
  __shared__ char lB[2][16384];
  int t = threadIdx.x;
  int lane = t & 63, w = t >> 6, l15 = lane & 15, grp = lane >> 4;
  int rt = blockIdx.x, kc = blockIdx.y;

  const char* Ab = connq + ((size_t)((rt * 16 + kc) * NBK) << 13);
  const char* Bb = Btq + ((size_t)(kc * NBK) << 14);

  float scj[4];
#pragma unroll
  for (int j = 0; j < 4; ++j) scj[j] = sc[kc * 64 + j * 16 + l15];

  bf16x8 ra[2][2], rb[2][4];
#pragma unroll
  for (int q = 0; q < 2; ++q) ra[0][q] = *(const bf16x8*)(Ab + q * 4096 + t * 16);
#pragma unroll
  for (int q = 0; q < 4; ++q) rb[0][q] = *(const bf16x8*)(Bb + q * 4096 + t * 16);
#pragma unroll
  for (int q = 0; q < 2; ++q) ra[1][q] = *(const bf16x8*)(Ab + TILE_A + q * 4096 + t * 16);
#pragma unroll
  for (int q = 0; q < 4; ++q) rb[1][q] = *(const bf16x8*)(Bb + SLAB_B + q * 4096 + t * 16);
#pragma unroll
  for (int q = 0; q < 2; ++q) *(bf16x8*)(&lA[0][0] + q * 4096 + t * 16) = ra[0][q];
#pragma unroll
  for (int q = 0; q < 4; ++q) *(bf16x8*)(&lB[0][0] + q * 4096 + t * 16) = rb[0][q];
  __syncthreads();

  i32x4 ah0 = {0,0,0,0}, ah1 = {0,0,0,0}, ah2 = {0,0,0,0}, ah3 = {0,0,0,0};
  i32x4 al0 = {0,0,0,0}, al1 = {0,0,0,0}, al2 = {0,0,0,0}, al3 = {0,0,0,0};
  const int arow = (w * 16 + l15) << 7;
  const int key  = l15 & 7;

#pragma unroll
  for (int bk = 0; bk < NBK; ++bk) {
    const int cur = bk & 1;
    const int nxt = cur ^ 1;
    if (bk + 2 < NBK) {
      const char* An = Ab + (size_t)(bk + 2) * TILE_A;
      const char* Bn = Bb + (size_t)(bk + 2) * SLAB_B;
#pragma unroll
      for (int q = 0; q < 2; ++q) ra[cur][q] = *(const bf16x8*)(An + q * 4096 + t * 16);
#pragma unroll
      for (int q = 0; q < 4; ++q) rb[cur][q] = *(const bf16x8*)(Bn + q * 4096 + t * 16);
    }
    const char* la = &lA[cur][0];
    const char* lb = &lB[cur][0];
#pragma unroll
    for (int ks = 0; ks < 2; ++ks) {
      const int cb = (((ks << 2) | grp) ^ key) << 4;
      i32x4 af = *(const i32x4*)(la + arow + cb);
      i32x4 bh0 = *(const i32x4*)(lb + ((0 * 16 + l15) << 7) + cb);
      i32x4 bh1 = *(const i32x4*)(lb + ((1 * 16 + l15) << 7) + cb);
      i32x4 bh2 = *(const i32x4*)(lb + ((2 * 16 + l15) << 7) + cb);
      i32x4 bh3 = *(const i32x4*)(lb + ((3 * 16 + l15) << 7) + cb);
      ah0 = __builtin_amdgcn_mfma_i32_16x16x64_i8(af, bh0, ah0, 0, 0, 0);
      ah1 = __builtin_amdgcn_mfma_i32_16x16x64_i8(af, bh1, ah1, 0, 0, 0);
      ah2 = __builtin_amdgcn_mfma_i32_16x16x64_i8(af, bh2, ah2, 0, 0, 0);
      ah3 = __builtin_amdgcn_mfma_i32_16x16x64_i8(af, bh3, ah3, 0, 0, 0);
      i32x4 bl0 = *(const i32x4*)(lb + 8192 + ((0 * 16 + l15) << 7) + cb);
      i32x4 bl1 = *(const i32x4*)(lb + 8192 + ((1 * 16 + l15) << 7) + cb);
      i32x4 bl2 = *(const i32x4*)(lb + 8192 + ((2 * 16 + l15) << 7) + cb);
      i32x4 bl3 = *(const i32x4*)(lb + 8192 + ((3 * 16 + l15) << 7) + cb);
      al0 = __builtin_amdgcn_mfma_i32_16x16x64_i8(af, bl0, al0, 0, 0, 0);
      al1 = __builtin_amdgcn_mfma_i32_16x16x64_i8(af, bl1, al1, 0, 0, 0);
      al2 = __builtin_amdgcn_mfma_i32_16x16x64_i8(af, bl2, al2, 0, 0, 0);
      al3 = __builtin_amdgcn_mfma_i32_16x16x64_i8(af, bl3, al3, 0, 0, 0);
    }
    if (bk + 1 < NBK) {
#pragma unroll
      for (int q = 0; q < 2; ++q) *(bf16x8*)(&lA[nxt][0] + q * 4096 + t * 16) = ra[nxt][q];
#pragma unroll
      for (int q = 0; q < 4; ++q) *(bf16x8*)(&lB[nxt][0] + q * 4096 + t * 16) = rb[nxt][q];
      __syncthreads();
    }
  }

  float* p = part + (size_t)kc * (A_N * D_N);
  int rbase = rt * 64 + w * 16 + grp * 4;
#pragma unroll
  for (int r = 0; r < 4; ++r) {
    float* pr = p + (size_t)(rbase + r) * D_N + l15;
    pr[0]  = ((float)ah0[r] + (float)al0[r] * (1.f/127.f)) * scj[0];
    pr[16] = ((float)ah1[r] + (float)al1[r] * (1.f/127.f)) * scj[1];
    pr[32] = ((float)ah2[r] + (float)al2[r] * (1.f/127.f)) * scj[2];
    pr[48] = ((float)ah3[r] + (float)al3[r] * (1.f/127.f)) * scj[3];
  }
}

// ---------- split-K reduce -> relu -> hb (bf16) ----------
template <int ADDX>
__global__ void k_reduce(const float* __restrict__ part, const float* __restrict__ bond,
                         const float* __restrict__ x, short* __restrict__ hb) {
  int i = blockIdx.x * 256 + threadIdx.x;   // 131072 total
  float s = bond[i];
#pragma unroll
  for (int si = 0; si < S_SPLIT; ++si) s += part[(size_t)si * (A_N * D_N) + i];
  if (ADDX) s += x[i];
  hb[i] = f2bf(fmaxf(s, 0.f));
}

// ---------- final reduce -> f32 out ----------
__global__ void k_final(const float* __restrict__ part, const float* __restrict__ bond,
                        const float* __restrict__ x, float* __restrict__ out) {
  int i = blockIdx.x * 256 + threadIdx.x;   // 131072 total
  float s = bond[i];
#pragma unroll
  for (int si = 0; si < S_SPLIT; ++si) s += part[(size_t)si * (A_N * D_N) + i];
  out[i] = fmaxf(s + x[i], 0.f);
}

// ---------- launch ----------
extern "C" void kernel_launch(void* const* d_in, const int* in_sizes, int n_in,
                              void* d_out, int out_size, void* d_ws, size_t ws_size,
                              hipStream_t stream) {
  const float* x    = (const float*)d_in[0];
  const float* conn = (const float*)d_in[1];
  const float* bprp = (const float*)d_in[2];
  const float* pf0  = (const float*)d_in[3];
  const float* bf0  = (const float*)d_in[4];
  const float* pf1  = (const float*)d_in[5];
  const float* bf1  = (const float*)d_in[6];
  float* out = (float*)d_out;

  char* ws = (char*)d_ws;
  size_t off = 0;
  char*  connq = (char*)(ws + off);  off += (size_t)A_N * KTOT;                 // 50.3 MB
  short* Btb   = (short*)(ws + off); off += (size_t)D_N * KTOT * 2;             // 3 MB
  char*  Btq   = (char*)(ws + off);  off += (size_t)D_N * KTOT * 2;             // 3 MB (hi+lo)
  float* sc    = (float*)(ws + off); off += (size_t)16 * 64 * 4;
  float* part  = (float*)(ws + off); off += (size_t)S_SPLIT * A_N * D_N * 4;    // 8.4 MB
  short* hb    = (short*)(ws + off); off += (size_t)A_N * D_N * 2;
  float* bond0 = (float*)(ws + off); off += (size_t)A_N * D_N * 4;
  float* bond1 = (float*)(ws + off); off += (size_t)A_N * D_N * 4;
  short* P2_0  = (short*)(ws + off); off += (size_t)D_N * FL_N * D_N * 2;
  short* P2_1  = (short*)(ws + off); off += (size_t)D_N * FL_N * D_N * 2;

  k_setup_cvt<<<4800, 256, 0, stream>>>(pf0, bf0, pf1, bf1, bprp, conn,
                                        P2_0, P2_1, bond0, bond1, connq);

  dim3 ggrid(32, S_SPLIT);

  // conv0: h = x
  k_prep0<<<128, 256, 0, stream>>>(x, P2_0, Btb);
  k_quantB<<<1024, 64, 0, stream>>>(Btb, Btq, sc);
  k_gemm<0><<<ggrid, 256, 0, stream>>>(connq, Btq, sc, part);

  // conv1: h1 = relu(conv0); bond0; P2_0
  k_reduce<0><<<512, 256, 0, stream>>>(part, bond0, x, hb);
  k_prepH<<<128, 256, 0, stream>>>(hb, P2_0, Btb);
  k_quantB<<<1024, 64, 0, stream>>>(Btb, Btq, sc);
  k_gemm<1><<<ggrid, 256, 0, stream>>>(connq, Btq, sc, part);

  // conv2: h2 = relu(conv1 + x); bond0; P2_1
  k_reduce<1><<<512, 256, 0, stream>>>(part, bond0, x, hb);
  k_prepH<<<128, 256, 0, stream>>>(hb, P2_1, Btb);
  k_quantB<<<1024, 64, 0, stream>>>(Btb, Btq, sc);
  k_gemm<2><<<ggrid, 256, 0, stream>>>(connq, Btq, sc, part);

  // conv3: h3 = relu(conv2); bond1; P2_1
  k_reduce<0><<<512, 256, 0, stream>>>(part, bond1, x, hb);
  k_prepH<<<128, 256, 0, stream>>>(hb, P2_1, Btb);
  k_quantB<<<1024, 64, 0, stream>>>(Btb, Btq, sc);
  k_gemm<3><<<ggrid, 256, 0, stream>>>(connq, Btq, sc, part);

  // out = relu(conv3 + bond1 + x)
  k_final<<<512, 256, 0, stream>>>(part, bond1, x, out);
}

// Round 15
// 165.151 us; speedup vs baseline: 1.1531x; 1.0808x over previous
//
#include <hip/hip_runtime.h>
#include <hip/hip_bf16.h>

#define A_N   2048
#define D_N   64
#define FL_N  12
#define KTOT  (A_N * FL_N)          // 24576
#define S_SPLIT 16
#define KCHUNK 1536                 // cols per kc-chunk (KTOT/16)
#define NBK   12                    // KCHUNK/128
#define TILE_A 8192                 // 64 rows * 128 k * 1B (i8)
#define SLAB_B 16384                // Btq slab: [hi 8KB][lo 8KB]

typedef __attribute__((ext_vector_type(8))) short bf16x8;
typedef __attribute__((ext_vector_type(4))) short bf16x4;
typedef __attribute__((ext_vector_type(4))) float f32x4;
typedef __attribute__((ext_vector_type(4))) int   i32x4;
typedef __attribute__((ext_vector_type(8))) char  i8x8;

__device__ __forceinline__ short f2bf(float f) {
  union { __hip_bfloat16 b; short s; } u;
  u.b = __float2bfloat16(f);
  return u.s;
}
__device__ __forceinline__ float bits2f(unsigned u) {
  union { unsigned u; float f; } c; c.u = u; return c.f;
}

// ---------- Bt prep body (bf16 MFMA) -> Btb bf16 slabs [o][k] linear ----------
__device__ __forceinline__ void prep_store(const f32x4* acc, short* __restrict__ Btb,
                                           int k0, int lane, int w) {
  int l15 = lane & 15, grp = lane >> 4;
#pragma unroll
  for (int r = 0; r < 4; ++r) {
    int o = w * 16 + grp * 4 + r;
    int katom = k0 + l15;
#pragma unroll
    for (int f = 0; f < FL_N; ++f) {
      int c = katom * FL_N + f;
      int kc = c / KCHUNK, rem = c % KCHUNK;
      int bk = rem >> 7, k = rem & 127;
      *(short*)((char*)Btb + ((size_t)(kc * NBK + bk) << 14) + (o << 8) + (k << 1))
          = f2bf(acc[f][r]);
    }
  }
}

__device__ __forceinline__ void prep_body(bf16x8 h0, bf16x8 h1,
                                          const short* __restrict__ P2,
                                          short* __restrict__ Btb,
                                          int k0, int lane, int w) {
  int l15 = lane & 15, grp = lane >> 4;
  const short* prow = P2 + (w * 16 + l15) * (FL_N * D_N) + grp * 8;
  f32x4 acc[FL_N];
#pragma unroll
  for (int f = 0; f < FL_N; ++f) {
    bf16x8 p0 = *(const bf16x8*)(prow + f * D_N);
    bf16x8 p1 = *(const bf16x8*)(prow + f * D_N + 32);
    f32x4 c = {0.f, 0.f, 0.f, 0.f};
    c = __builtin_amdgcn_mfma_f32_16x16x32_bf16(p0, h0, c, 0, 0, 0);
    c = __builtin_amdgcn_mfma_f32_16x16x32_bf16(p1, h1, c, 0, 0, 0);
    acc[f] = c;
  }
  prep_store(acc, Btb, k0, lane, w);
}

// ---------- fused setup: P2, bond, conv0-prep, conn -> i8 tiled+swizzled ----------
// blocks [0,192): P2; [192,704): bond; [704,832): prep0 (reads x/pf0/bf0 directly);
// [832,4928): connq cvt.
__global__ void k_setup(const float* __restrict__ pf0, const float* __restrict__ bf0,
                        const float* __restrict__ pf1, const float* __restrict__ bf1,
                        const float* __restrict__ bp, const float* __restrict__ x,
                        const float* __restrict__ conn,
                        short* __restrict__ P2_0, short* __restrict__ P2_1,
                        float* __restrict__ bond0, float* __restrict__ bond1,
                        char* __restrict__ connq, short* __restrict__ Btb) {
  int b = blockIdx.x, t = threadIdx.x;
  if (b >= 832) {
    size_t slot = (size_t)(b - 832) * 256 + t;        // < 1048576
#pragma unroll
    for (int cc = 0; cc < 6; ++cc) {
      size_t i = (slot + (size_t)cc * 1048576) * 8;   // covers 50331648 floats exactly
      f32x4 a0 = __builtin_nontemporal_load((const f32x4*)(conn + i));
      f32x4 a1 = __builtin_nontemporal_load((const f32x4*)(conn + i + 4));
      i8x8 v;
      v[0]=(char)rintf(a0[0]*127.f); v[1]=(char)rintf(a0[1]*127.f);
      v[2]=(char)rintf(a0[2]*127.f); v[3]=(char)rintf(a0[3]*127.f);
      v[4]=(char)rintf(a1[0]*127.f); v[5]=(char)rintf(a1[1]*127.f);
      v[6]=(char)rintf(a1[2]*127.f); v[7]=(char)rintf(a1[3]*127.f);
      int a = (int)(i / KTOT), c = (int)(i % KTOT);
      int rt = a >> 6, r = a & 63;
      int kc = c / KCHUNK, rem = c % KCHUNK;
      int bk = rem >> 7, k = rem & 127;
      int phys = (k >> 4) ^ (r & 7);
      size_t dst = ((size_t)((rt * 16 + kc) * NBK + bk) << 13)
                   + (r << 7) + (phys << 4) + (k & 15);
      *(i8x8*)(connq + dst) = v;
    }
    return;
  }
  if (b < 192) {
    int idx = b * 256 + t;                       // < 49152
    int f = (idx >> 6) % FL_N;
    int o = idx / (D_N * FL_N);
    P2_0[idx] = f2bf(pf0[idx] * bf0[(o * FL_N + f) * 3]);
    P2_1[idx] = f2bf(pf1[idx] * bf1[(o * FL_N + f) * 3]);
    return;
  }
  if (b < 704) {
    int o = t & 63;
    int a = (b - 192) * 4 + (t >> 6);
    float s0 = 0.f, s1 = 0.f;
#pragma unroll
    for (int f = 0; f < FL_N; ++f) {
      float c0 = bp[(a * FL_N + f) * 2 + 0];
      float c1 = bp[(a * FL_N + f) * 2 + 1];
      s0 += c0 * bf0[(o * FL_N + f) * 3 + 1] + c1 * bf0[(o * FL_N + f) * 3 + 2];
      s1 += c0 * bf1[(o * FL_N + f) * 3 + 1] + c1 * bf1[(o * FL_N + f) * 3 + 2];
    }
    bond0[a * D_N + o] = s0;
    bond1[a * D_N + o] = s1;
    return;
  }
  // prep0 for conv0: blocks [704,832), k0 = (b-704)*16; reads x f32 and pf0/bf0
  {
    int lane = t & 63, w = t >> 6, l15 = lane & 15, grp = lane >> 4;
    int k0 = (b - 704) * 16;
    const float* hrow = x + (k0 + l15) * D_N + grp * 8;
    f32x4 x0 = *(const f32x4*)(hrow);
    f32x4 x1 = *(const f32x4*)(hrow + 4);
    f32x4 x2 = *(const f32x4*)(hrow + 32);
    f32x4 x3 = *(const f32x4*)(hrow + 36);
    bf16x8 h0, h1;
    h0[0]=f2bf(x0[0]); h0[1]=f2bf(x0[1]); h0[2]=f2bf(x0[2]); h0[3]=f2bf(x0[3]);
    h0[4]=f2bf(x1[0]); h0[5]=f2bf(x1[1]); h0[6]=f2bf(x1[2]); h0[7]=f2bf(x1[3]);
    h1[0]=f2bf(x2[0]); h1[1]=f2bf(x2[1]); h1[2]=f2bf(x2[2]); h1[3]=f2bf(x2[3]);
    h1[4]=f2bf(x3[0]); h1[5]=f2bf(x3[1]); h1[6]=f2bf(x3[2]); h1[7]=f2bf(x3[3]);
    // inline P2: p = bf16(pf0 * bf0[...,0]) -- no dependency on P2 buffers
    int orow = w * 16 + l15;
    f32x4 acc[FL_N];
#pragma unroll
    for (int f = 0; f < FL_N; ++f) {
      const float* pr = pf0 + (orow * FL_N + f) * D_N + grp * 8;
      float s = bf0[(orow * FL_N + f) * 3];
      f32x4 q0 = *(const f32x4*)(pr);
      f32x4 q1 = *(const f32x4*)(pr + 4);
      f32x4 q2 = *(const f32x4*)(pr + 32);
      f32x4 q3 = *(const f32x4*)(pr + 36);
      bf16x8 p0, p1;
      p0[0]=f2bf(q0[0]*s); p0[1]=f2bf(q0[1]*s); p0[2]=f2bf(q0[2]*s); p0[3]=f2bf(q0[3]*s);
      p0[4]=f2bf(q1[0]*s); p0[5]=f2bf(q1[1]*s); p0[6]=f2bf(q1[2]*s); p0[7]=f2bf(q1[3]*s);
      p1[0]=f2bf(q2[0]*s); p1[1]=f2bf(q2[1]*s); p1[2]=f2bf(q2[2]*s); p1[3]=f2bf(q2[3]*s);
      p1[4]=f2bf(q3[0]*s); p1[5]=f2bf(q3[1]*s); p1[6]=f2bf(q3[2]*s); p1[7]=f2bf(q3[3]*s);
      f32x4 c = {0.f, 0.f, 0.f, 0.f};
      c = __builtin_amdgcn_mfma_f32_16x16x32_bf16(p0, h0, c, 0, 0, 0);
      c = __builtin_amdgcn_mfma_f32_16x16x32_bf16(p1, h1, c, 0, 0, 0);
      acc[f] = c;
    }
    prep_store(acc, Btb, k0, lane, w);
  }
}

// ---------- fused reduce+prep (conv c>0): 128 blocks ----------
template <int ADDX>
__global__ void k_prep_r(const float* __restrict__ part, const float* __restrict__ bond,
                         const float* __restrict__ x, const short* __restrict__ P2,
                         short* __restrict__ Btb) {
  __shared__ short hsh[16 * 64];
  int t = threadIdx.x;
  int k0 = blockIdx.x * 16;
  int r  = t >> 4;
  int d0 = (t & 15) * 4;
  size_t base = (size_t)(k0 + r) * D_N + d0;
  f32x4 s = *(const f32x4*)(bond + base);
#pragma unroll
  for (int si = 0; si < S_SPLIT; ++si) {
    f32x4 p = *(const f32x4*)(part + (size_t)si * (A_N * D_N) + base);
    s[0] += p[0]; s[1] += p[1]; s[2] += p[2]; s[3] += p[3];
  }
  if (ADDX) {
    f32x4 xv = *(const f32x4*)(x + base);
    s[0] += xv[0]; s[1] += xv[1]; s[2] += xv[2]; s[3] += xv[3];
  }
  bf16x4 hv;
  hv[0] = f2bf(fmaxf(s[0], 0.f)); hv[1] = f2bf(fmaxf(s[1], 0.f));
  hv[2] = f2bf(fmaxf(s[2], 0.f)); hv[3] = f2bf(fmaxf(s[3], 0.f));
  *(bf16x4*)(&hsh[r * 64 + d0]) = hv;
  __syncthreads();
  int lane = t & 63, w = t >> 6, l15 = lane & 15, grp = lane >> 4;
  bf16x8 h0 = *(const bf16x8*)(&hsh[l15 * 64 + grp * 8]);
  bf16x8 h1 = *(const bf16x8*)(&hsh[l15 * 64 + grp * 8 + 32]);
  prep_body(h0, h1, P2, Btb, k0, lane, w);
}

// ---------- quantB: Btb bf16 -> dual-plane i8 (swizzled) + per-(o,kc) scale ----------
__global__ void k_quantB(const short* __restrict__ Btb, char* __restrict__ Btq,
                         float* __restrict__ sc) {
  int b = blockIdx.x, t = threadIdx.x;
  int kc = b >> 6, o = b & 63;
  float v0[NBK], v1[NBK];
  float m = 0.f;
#pragma unroll
  for (int bk = 0; bk < NBK; ++bk) {
    unsigned sv = *(const unsigned*)((const char*)Btb
                   + ((size_t)(kc * NBK + bk) << 14) + (o << 8) + (t << 2));
    float f0 = bits2f(sv << 16);
    float f1 = bits2f(sv & 0xFFFF0000u);
    v0[bk] = f0; v1[bk] = f1;
    m = fmaxf(m, fmaxf(fabsf(f0), fabsf(f1)));
  }
#pragma unroll
  for (int off = 1; off < 64; off <<= 1) m = fmaxf(m, __shfl_xor(m, off));
  float inv = (m > 1e-30f) ? (127.f / m) : 0.f;
  if (t == 0) sc[kc * 64 + o] = m * (1.f / 16129.f);   // m/(127*127)
  int k = 2 * t;
  int phys = ((k >> 4) ^ (o & 7));
  int boff = (o << 7) + (phys << 4) + (k & 15);
#pragma unroll
  for (int bk = 0; bk < NBK; ++bk) {
    float s0 = v0[bk] * inv, s1 = v1[bk] * inv;
    float h0 = rintf(s0), h1 = rintf(s1);
    char q0 = (char)h0, q1 = (char)h1;
    char l0 = (char)rintf((s0 - h0) * 127.f);
    char l1 = (char)rintf((s1 - h1) * 127.f);
    char* base = Btq + ((size_t)(kc * NBK + bk) << 14);
    *(short*)(base + boff) = (short)(((unsigned char)q0) | (((unsigned)(unsigned char)q1) << 8));
    *(short*)(base + 8192 + boff) = (short)(((unsigned char)l0) | (((unsigned)(unsigned char)l1) << 8));
  }
}

// ---------- big GEMM: i8 MFMA, LDS dbuf, depth-2 reg prefetch (R14, unchanged) ----------
template <int C>
__global__ __launch_bounds__(256, 2) void k_gemm(const char* __restrict__ connq,
                                                 const char* __restrict__ Btq,
                                                 const float* __restrict__ sc,
                                                 float* __restrict__ part) {
  __shared__ char lA[2][8192];
  __shared__ char lB[2][16384];
  int t = threadIdx.x;
  int lane = t & 63, w = t >> 6, l15 = lane & 15, grp = lane >> 4;
  int rt = blockIdx.x, kc = blockIdx.y;

  const char* Ab = connq + ((size_t)((rt * 16 + kc) * NBK) << 13);
  const char* Bb = Btq + ((size_t)(kc * NBK) << 14);

  float scj[4];
#pragma unroll
  for (int j = 0; j < 4; ++j) scj[j] = sc[kc * 64 + j * 16 + l15];

  bf16x8 ra[2][2], rb[2][4];
#pragma unroll
  for (int q = 0; q < 2; ++q) ra[0][q] = *(const bf16x8*)(Ab + q * 4096 + t * 16);
#pragma unroll
  for (int q = 0; q < 4; ++q) rb[0][q] = *(const bf16x8*)(Bb + q * 4096 + t * 16);
#pragma unroll
  for (int q = 0; q < 2; ++q) ra[1][q] = *(const bf16x8*)(Ab + TILE_A + q * 4096 + t * 16);
#pragma unroll
  for (int q = 0; q < 4; ++q) rb[1][q] = *(const bf16x8*)(Bb + SLAB_B + q * 4096 + t * 16);
#pragma unroll
  for (int q = 0; q < 2; ++q) *(bf16x8*)(&lA[0][0] + q * 4096 + t * 16) = ra[0][q];
#pragma unroll
  for (int q = 0; q < 4; ++q) *(bf16x8*)(&lB[0][0] + q * 4096 + t * 16) = rb[0][q];
  __syncthreads();

  i32x4 ah0 = {0,0,0,0}, ah1 = {0,0,0,0}, ah2 = {0,0,0,0}, ah3 = {0,0,0,0};
  i32x4 al0 = {0,0,0,0}, al1 = {0,0,0,0}, al2 = {0,0,0,0}, al3 = {0,0,0,0};
  const int arow = (w * 16 + l15) << 7;
  const int key  = l15 & 7;

#pragma unroll
  for (int bk = 0; bk < NBK; ++bk) {
    const int cur = bk & 1;
    const int nxt = cur ^ 1;
    if (bk + 2 < NBK) {
      const char* An = Ab + (size_t)(bk + 2) * TILE_A;
      const char* Bn = Bb + (size_t)(bk + 2) * SLAB_B;
#pragma unroll
      for (int q = 0; q < 2; ++q) ra[cur][q] = *(const bf16x8*)(An + q * 4096 + t * 16);
#pragma unroll
      for (int q = 0; q < 4; ++q) rb[cur][q] = *(const bf16x8*)(Bn + q * 4096 + t * 16);
    }
    const char* la = &lA[cur][0];
    const char* lb = &lB[cur][0];
#pragma unroll
    for (int ks = 0; ks < 2; ++ks) {
      const int cb = (((ks << 2) | grp) ^ key) << 4;
      i32x4 af = *(const i32x4*)(la + arow + cb);
      i32x4 bh0 = *(const i32x4*)(lb + ((0 * 16 + l15) << 7) + cb);
      i32x4 bh1 = *(const i32x4*)(lb + ((1 * 16 + l15) << 7) + cb);
      i32x4 bh2 = *(const i32x4*)(lb + ((2 * 16 + l15) << 7) + cb);
      i32x4 bh3 = *(const i32x4*)(lb + ((3 * 16 + l15) << 7) + cb);
      ah0 = __builtin_amdgcn_mfma_i32_16x16x64_i8(af, bh0, ah0, 0, 0, 0);
      ah1 = __builtin_amdgcn_mfma_i32_16x16x64_i8(af, bh1, ah1, 0, 0, 0);
      ah2 = __builtin_amdgcn_mfma_i32_16x16x64_i8(af, bh2, ah2, 0, 0, 0);
      ah3 = __builtin_amdgcn_mfma_i32_16x16x64_i8(af, bh3, ah3, 0, 0, 0);
      i32x4 bl0 = *(const i32x4*)(lb + 8192 + ((0 * 16 + l15) << 7) + cb);
      i32x4 bl1 = *(const i32x4*)(lb + 8192 + ((1 * 16 + l15) << 7) + cb);
      i32x4 bl2 = *(const i32x4*)(lb + 8192 + ((2 * 16 + l15) << 7) + cb);
      i32x4 bl3 = *(const i32x4*)(lb + 8192 + ((3 * 16 + l15) << 7) + cb);
      al0 = __builtin_amdgcn_mfma_i32_16x16x64_i8(af, bl0, al0, 0, 0, 0);
      al1 = __builtin_amdgcn_mfma_i32_16x16x64_i8(af, bl1, al1, 0, 0, 0);
      al2 = __builtin_amdgcn_mfma_i32_16x16x64_i8(af, bl2, al2, 0, 0, 0);
      al3 = __builtin_amdgcn_mfma_i32_16x16x64_i8(af, bl3, al3, 0, 0, 0);
    }
    if (bk + 1 < NBK) {
#pragma unroll
      for (int q = 0; q < 2; ++q) *(bf16x8*)(&lA[nxt][0] + q * 4096 + t * 16) = ra[nxt][q];
#pragma unroll
      for (int q = 0; q < 4; ++q) *(bf16x8*)(&lB[nxt][0] + q * 4096 + t * 16) = rb[nxt][q];
      __syncthreads();
    }
  }

  float* p = part + (size_t)kc * (A_N * D_N);
  int rbase = rt * 64 + w * 16 + grp * 4;
#pragma unroll
  for (int r = 0; r < 4; ++r) {
    float* pr = p + (size_t)(rbase + r) * D_N + l15;
    pr[0]  = ((float)ah0[r] + (float)al0[r] * (1.f/127.f)) * scj[0];
    pr[16] = ((float)ah1[r] + (float)al1[r] * (1.f/127.f)) * scj[1];
    pr[32] = ((float)ah2[r] + (float)al2[r] * (1.f/127.f)) * scj[2];
    pr[48] = ((float)ah3[r] + (float)al3[r] * (1.f/127.f)) * scj[3];
  }
}

// ---------- final reduce -> f32 out ----------
__global__ void k_final(const float* __restrict__ part, const float* __restrict__ bond,
                        const float* __restrict__ x, float* __restrict__ out) {
  int i = blockIdx.x * 256 + threadIdx.x;   // 131072 total
  float s = bond[i];
#pragma unroll
  for (int si = 0; si < S_SPLIT; ++si) s += part[(size_t)si * (A_N * D_N) + i];
  out[i] = fmaxf(s + x[i], 0.f);
}

// ---------- launch ----------
extern "C" void kernel_launch(void* const* d_in, const int* in_sizes, int n_in,
                              void* d_out, int out_size, void* d_ws, size_t ws_size,
                              hipStream_t stream) {
  const float* x    = (const float*)d_in[0];
  const float* conn = (const float*)d_in[1];
  const float* bprp = (const float*)d_in[2];
  const float* pf0  = (const float*)d_in[3];
  const float* bf0  = (const float*)d_in[4];
  const float* pf1  = (const float*)d_in[5];
  const float* bf1  = (const float*)d_in[6];
  float* out = (float*)d_out;

  char* ws = (char*)d_ws;
  size_t off = 0;
  char*  connq = (char*)(ws + off);  off += (size_t)A_N * KTOT;                 // 50.3 MB
  short* Btb   = (short*)(ws + off); off += (size_t)D_N * KTOT * 2;             // 3 MB
  char*  Btq   = (char*)(ws + off);  off += (size_t)D_N * KTOT * 2;             // 3 MB (hi+lo)
  float* sc    = (float*)(ws + off); off += (size_t)16 * 64 * 4;
  float* part  = (float*)(ws + off); off += (size_t)S_SPLIT * A_N * D_N * 4;    // 8.4 MB
  float* bond0 = (float*)(ws + off); off += (size_t)A_N * D_N * 4;
  float* bond1 = (float*)(ws + off); off += (size_t)A_N * D_N * 4;
  short* P2_0  = (short*)(ws + off); off += (size_t)D_N * FL_N * D_N * 2;
  short* P2_1  = (short*)(ws + off); off += (size_t)D_N * FL_N * D_N * 2;

  dim3 ggrid(32, S_SPLIT);

  // setup: P2, bond, conv0-prep (inline P2), conn->i8
  k_setup<<<4928, 256, 0, stream>>>(pf0, bf0, pf1, bf1, bprp, x, conn,
                                    P2_0, P2_1, bond0, bond1, connq, Btb);

  // conv0
  k_quantB<<<1024, 64, 0, stream>>>(Btb, Btq, sc);
  k_gemm<0><<<ggrid, 256, 0, stream>>>(connq, Btq, sc, part);

  // conv1: h1 = relu(conv0); bond0; P2_0
  k_prep_r<0><<<128, 256, 0, stream>>>(part, bond0, x, P2_0, Btb);
  k_quantB<<<1024, 64, 0, stream>>>(Btb, Btq, sc);
  k_gemm<1><<<ggrid, 256, 0, stream>>>(connq, Btq, sc, part);

  // conv2: h2 = relu(conv1 + x); bond0; P2_1
  k_prep_r<1><<<128, 256, 0, stream>>>(part, bond0, x, P2_1, Btb);
  k_quantB<<<1024, 64, 0, stream>>>(Btb, Btq, sc);
  k_gemm<2><<<ggrid, 256, 0, stream>>>(connq, Btq, sc, part);

  // conv3: h3 = relu(conv2); bond1; P2_1
  k_prep_r<0><<<128, 256, 0, stream>>>(part, bond1, x, P2_1, Btb);
  k_quantB<<<1024, 64, 0, stream>>>(Btb, Btq, sc);
  k_gemm<3><<<ggrid, 256, 0, stream>>>(connq, Btq, sc, part);

  // out = relu(conv3 + bond1 + x)
  k_final<<<512, 256, 0, stream>>>(part, bond1, x, out);
}